// Round 6
// baseline (98.303 us; speedup 1.0000x reference)
//
#include <hip/hip_runtime.h>

// A8W8 GEMM, fp16-saturating output. C = (a_i8 @ b_i8^T) * arow * acol.
// Pass 1: pack int32 -> int8. Pass 2: 256x256 tile, BKB=128, 8 waves,
// m201-faithful 4-phase/K-tile grammar: per phase {ds_reads (4-8), stage
// (0-4 gload_lds), counted vmcnt, BARRIER, 16 MFMA under setprio,
// BARRIER}. Double-buffered LDS, both-sides XOR swizzle slot^=(row&7).

constexpr int MD = 4096, ND = 4096, KD = 4096;
constexpr int BM = 256, BN = 256, BKB = 128;  // K-tile bytes (128 i8)
constexpr int NT = KD / BKB;                  // 32 K-tiles
constexpr int TB = BM * BKB;                  // 32 KiB per matrix per buffer

using i32x4 = __attribute__((ext_vector_type(4))) int;

#define VMCNT(n) asm volatile("s_waitcnt vmcnt(" #n ")" ::: "memory")
#define BAR() __builtin_amdgcn_s_barrier()

// ---------------- pack: int32 (one value per elem) -> int8 ----------------
__global__ __launch_bounds__(256) void pack_i8(const int* __restrict__ in,
                                               char* __restrict__ out) {
  const size_t t = (size_t)blockIdx.x * 256 + threadIdx.x;
  const int4* p = (const int4*)in + t * 4;
  int4 v0 = p[0], v1 = p[1], v2 = p[2], v3 = p[3];
  int4 o;
  o.x = v0.x | (v0.y << 8) | (v0.z << 16) | (v0.w << 24);
  o.y = v1.x | (v1.y << 8) | (v1.z << 16) | (v1.w << 24);
  o.z = v2.x | (v2.y << 8) | (v2.z << 16) | (v2.w << 24);
  o.w = v3.x | (v3.y << 8) | (v3.z << 16) | (v3.w << 24);
  ((int4*)out)[t] = o;
}

// ---------------- GEMM ----------------------------------------------------
__device__ inline void load16_lds(const char* g, char* l) {
  __builtin_amdgcn_global_load_lds(
      (const __attribute__((address_space(1))) void*)g,
      (__attribute__((address_space(3))) void*)l, 16, 0, 0);
}

// reference fp16 cast, saturating (all values >= 0; |inf-finite|=inf passes)
__device__ inline float f16_sat(float v) {
  v = fminf(v, 65504.0f);
  return (float)(_Float16)v;
}

__global__ __launch_bounds__(512, 2) void gemm_i8w8(
    const char* __restrict__ A, const char* __restrict__ B,
    const float* __restrict__ arow, const float* __restrict__ acol,
    float* __restrict__ out) {
  __shared__ char sA[2][TB];  // 64 KiB
  __shared__ char sB[2][TB];  // 64 KiB

  const int tid = threadIdx.x;
  const int wv = tid >> 6;
  const int lane = tid & 63;

  // XCD-aware bijective swizzle (nwg = 256, divisible by 8)
  const int bid = blockIdx.x;
  const int wg = (bid & 7) * 32 + (bid >> 3);
  const int brow = wg >> 4;
  const int bcol = wg & 15;

  // 2(M) x 4(N) wave grid; per-wave output 128 x 64
  const int wrow = (wv >> 2) * 128;
  const int wcol = (wv & 3) * 64;

  i32x4 acc[8][4] = {};

  // ---- staging geometry (verified): each gload_lds = 8 rows x 128B;
  // LDS dest linear (lane l -> row +(l>>3), slot l&7); source slot
  // pre-swizzled (l&7)^(l>>3) so LDS[row][s] = G[row][s^(row&7)].
  const int lr = lane >> 3;
  const int lsg = ((lane & 7) ^ lr) * 16;
  const int q0 = wv * 2, q1 = wv * 2 + 1;
  const int rA0 = (q0 >> 3) * 128 + (q0 & 7) * 8;  // A rows {0-63,128-191}
  const int rA1 = (q1 >> 3) * 128 + (q1 & 7) * 8;
  const int rB0 = (q0 >> 2) * 64 + (q0 & 3) * 8;   // B rows {first 32 of 64}
  const int rB1 = (q1 >> 2) * 64 + (q1 & 3) * 8;
  const char* srcA0 = A + (size_t)(brow * BM + rA0 + lr) * KD + lsg;
  const char* srcA1 = A + (size_t)(brow * BM + rA1 + lr) * KD + lsg;
  const char* srcB0 = B + (size_t)(bcol * BN + rB0 + lr) * KD + lsg;
  const char* srcB1 = B + (size_t)(bcol * BN + rB1 + lr) * KD + lsg;
  const size_t skip32 = (size_t)32 * KD, skip64 = (size_t)64 * KD;

  auto STAGE_UA0 = [&](int nb, size_t kb) {  // A rows for m0-3 (2 loads)
    load16_lds(srcA0 + kb, sA[nb] + rA0 * BKB);
    load16_lds(srcA1 + kb, sA[nb] + rA1 * BKB);
  };
  auto STAGE_UB0 = [&](int nb, size_t kb) {  // B rows for n0-1 (2 loads)
    load16_lds(srcB0 + kb, sB[nb] + rB0 * BKB);
    load16_lds(srcB1 + kb, sB[nb] + rB1 * BKB);
  };
  auto STAGE_UB1 = [&](int nb, size_t kb) {  // B rows for n2-3 (2 loads)
    load16_lds(srcB0 + skip32 + kb, sB[nb] + (rB0 + 32) * BKB);
    load16_lds(srcB1 + skip32 + kb, sB[nb] + (rB1 + 32) * BKB);
  };
  auto STAGE_UA1 = [&](int nb, size_t kb) {  // A rows for m4-7 (2 loads)
    load16_lds(srcA0 + skip64 + kb, sA[nb] + (rA0 + 64) * BKB);
    load16_lds(srcA1 + skip64 + kb, sA[nb] + (rA1 + 64) * BKB);
  };

  // ---- fragment reads: row = base + (lane&15); G-slot = ks*4+(lane>>4);
  // LDS slot = G-slot ^ (r&7).
  const int r = lane & 15;
  const int s0 = (((lane >> 4) + 0) ^ (r & 7)) * 16;  // ks=0
  const int s1 = (((lane >> 4) + 4) ^ (r & 7)) * 16;  // ks=1
  const int aBase = (wrow + r) * BKB;                 // + m*2048
  const int bBase = (wcol + r) * BKB;                 // + n*2048

  // ---- prologue: stage tile 0 (FIFO: uA0,uB0 | uB1 | uA1), retire
  // uA0+uB0, publish, pre-read bf01[0].
  STAGE_UA0(0, 0);
  STAGE_UB0(0, 0);
  STAGE_UB1(0, 0);
  STAGE_UA1(0, 0);
  VMCNT(4);  // uA0(0), uB0(0) landed; {uB1(0), uA1(0)} in flight
  BAR();

  i32x4 af[4][2], bf01[2][2], bf23[2][2];
#pragma unroll
  for (int n = 0; n < 2; ++n) {
    bf01[n][0] = *(const i32x4*)(sB[0] + bBase + n * 2048 + s0);
    bf01[n][1] = *(const i32x4*)(sB[0] + bBase + n * 2048 + s1);
  }

  for (int i = 0; i < NT; ++i) {
    const int cb = i & 1, nb = cb ^ 1;
    const size_t kb = (size_t)(i + 1) * BKB;
    const char* pa = sA[cb] + aBase;
    const char* pb = sB[cb] + bBase;
    const char* pbn = sB[nb] + bBase;
    const bool more = (i + 1) < NT;

    // ===== P1: read af0-3; stage uA0',uB0'; vmcnt; BAR; Q1; BAR =====
#pragma unroll
    for (int m = 0; m < 4; ++m) {
      af[m][0] = *(const i32x4*)(pa + m * 2048 + s0);
      af[m][1] = *(const i32x4*)(pa + m * 2048 + s1);
    }
    if (more) {
      STAGE_UA0(nb, kb);
      STAGE_UB0(nb, kb);
      VMCNT(6);  // retire uB1(i)  [read @P2]
    } else {
      VMCNT(2);  // tail: retire uB1(i), keep uA1(i)
    }
    BAR();
    __builtin_amdgcn_s_setprio(1);
#pragma unroll
    for (int ks = 0; ks < 2; ++ks)
#pragma unroll
      for (int m = 0; m < 4; ++m)
#pragma unroll
        for (int n = 0; n < 2; ++n)
          acc[m][n] = __builtin_amdgcn_mfma_i32_16x16x64_i8(
              af[m][ks], bf01[n][ks], acc[m][n], 0, 0, 0);
    __builtin_amdgcn_s_setprio(0);
    BAR();

    // ===== P2: read bf23; stage uB1'; vmcnt; BAR; Q2; BAR =====
#pragma unroll
    for (int n = 0; n < 2; ++n) {
      bf23[n][0] = *(const i32x4*)(pb + (n + 2) * 2048 + s0);
      bf23[n][1] = *(const i32x4*)(pb + (n + 2) * 2048 + s1);
    }
    if (more) {
      STAGE_UB1(nb, kb);
      VMCNT(6);  // retire uA1(i)  [read @P3]
    } else {
      VMCNT(0);  // tail: retire uA1(i)
    }
    BAR();
    __builtin_amdgcn_s_setprio(1);
#pragma unroll
    for (int ks = 0; ks < 2; ++ks)
#pragma unroll
      for (int m = 0; m < 4; ++m)
#pragma unroll
        for (int n = 0; n < 2; ++n)
          acc[m][n + 2] = __builtin_amdgcn_mfma_i32_16x16x64_i8(
              af[m][ks], bf23[n][ks], acc[m][n + 2], 0, 0, 0);
    __builtin_amdgcn_s_setprio(0);
    BAR();

    // ===== P3: read af4-7; stage uA1'; vmcnt; BAR; Q3; BAR =====
#pragma unroll
    for (int m = 0; m < 4; ++m) {
      af[m][0] = *(const i32x4*)(pa + (m + 4) * 2048 + s0);
      af[m][1] = *(const i32x4*)(pa + (m + 4) * 2048 + s1);
    }
    if (more) {
      STAGE_UA1(nb, kb);
      VMCNT(4);  // retire uA0',uB0'  [uB0' read @P4, uA0' @next P1]
    }
    BAR();
    __builtin_amdgcn_s_setprio(1);
#pragma unroll
    for (int ks = 0; ks < 2; ++ks)
#pragma unroll
      for (int m = 0; m < 4; ++m)
#pragma unroll
        for (int n = 0; n < 2; ++n)
          acc[m + 4][n] = __builtin_amdgcn_mfma_i32_16x16x64_i8(
              af[m][ks], bf01[n][ks], acc[m + 4][n], 0, 0, 0);
    __builtin_amdgcn_s_setprio(0);
    BAR();

    // ===== P4: read bf01<-next buffer; BAR; Q4; BAR =====
    if (more) {
#pragma unroll
      for (int n = 0; n < 2; ++n) {
        bf01[n][0] = *(const i32x4*)(pbn + n * 2048 + s0);
        bf01[n][1] = *(const i32x4*)(pbn + n * 2048 + s1);
      }
    }
    BAR();
    __builtin_amdgcn_s_setprio(1);
#pragma unroll
    for (int ks = 0; ks < 2; ++ks)
#pragma unroll
      for (int m = 0; m < 4; ++m)
#pragma unroll
        for (int n = 0; n < 2; ++n)
          acc[m + 4][n + 2] = __builtin_amdgcn_mfma_i32_16x16x64_i8(
              af[m][ks], bf23[n][ks], acc[m + 4][n + 2], 0, 0, 0);
    __builtin_amdgcn_s_setprio(0);
    BAR();
  }

  // ---- epilogue: C/D map col=lane&15, row=(lane>>4)*4+reg (16x16 shapes)
  const int orow0 = brow * BM + wrow + ((lane >> 4) << 2);
  const int ocol0 = bcol * BN + wcol + (lane & 15);
#pragma unroll
  for (int m = 0; m < 8; ++m) {
    const int rb = orow0 + m * 16;
    const float ar0 = arow[rb + 0], ar1 = arow[rb + 1];
    const float ar2 = arow[rb + 2], ar3 = arow[rb + 3];
#pragma unroll
    for (int n = 0; n < 4; ++n) {
      const int col = ocol0 + n * 16;
      const float ac = acol[col];
      out[(size_t)(rb + 0) * ND + col] = f16_sat((float)acc[m][n][0] * (ar0 * ac));
      out[(size_t)(rb + 1) * ND + col] = f16_sat((float)acc[m][n][1] * (ar1 * ac));
      out[(size_t)(rb + 2) * ND + col] = f16_sat((float)acc[m][n][2] * (ar2 * ac));
      out[(size_t)(rb + 3) * ND + col] = f16_sat((float)acc[m][n][3] * (ar3 * ac));
    }
  }
}

extern "C" void kernel_launch(void* const* d_in, const int* in_sizes, int n_in,
                              void* d_out, int out_size, void* d_ws, size_t ws_size,
                              hipStream_t stream) {
  const int* a = (const int*)d_in[0];         // [M,K] int32 (int8 values)
  const int* b = (const int*)d_in[1];         // [N,K] int32 (int8 values)
  const float* arow = (const float*)d_in[2];  // [M,1]
  const float* acol = (const float*)d_in[3];  // [1,N]
  float* out = (float*)d_out;

  char* pa = (char*)d_ws;                    // 16 MiB packed A
  char* pb = pa + (size_t)MD * KD;           // 16 MiB packed B

  const int packBlocks = (int)(((size_t)MD * KD) / (16 * 256));  // 4096
  pack_i8<<<packBlocks, 256, 0, stream>>>(a, pa);
  pack_i8<<<packBlocks, 256, 0, stream>>>(b, pb);

  const int grid = (MD / BM) * (ND / BN);  // 256 blocks, 1 per CU
  gemm_i8w8<<<grid, 512, 0, stream>>>(pa, pb, arow, acol, out);
}